// Round 4
// baseline (294.745 us; speedup 1.0000x reference)
//
#include <hip/hip_runtime.h>

#define N_NODES 600
#define NSUP    520
#define NQ      80
#define C_CLS   5
#define PER     104
#define F_IN    1024
#define EMBF    128
#define FE      256
#define CATD    261
#define CST     264   // padded stride of cated
#define FCD     510
#define FCST    512
#define CONV_OUT 254  // FE - K + 1

// csum[c][k] = sum over the 104 rows of class c of X[r][k]; X is [600][1024]
__global__ void csum1024_k(const float* __restrict__ X, float* __restrict__ csum) {
    const int c = blockIdx.y;
    const int k = blockIdx.x * 256 + threadIdx.x;   // grid (4,5) x 256
    float s = 0.f;
    for (int j = 0; j < PER; ++j) s += X[(c * PER + j) * F_IN + k];
    csum[c * F_IN + k] = s;
}

// supports class c: cated[r][ooff+f] = leaky(csum[c]·W[:,f]/104 + b[f])
__global__ void supp_emb_k(const float* __restrict__ csum, const float* __restrict__ W,
                           const float* __restrict__ b, float* __restrict__ cated, int ooff) {
    const int c = blockIdx.x, f = threadIdx.x;      // 5 x 128
    float acc = 0.f;
    for (int k = 0; k < F_IN; ++k) acc += csum[c * F_IN + k] * W[k * EMBF + f];
    float v = acc * (1.0f / PER) + b[f];
    v = v > 0.f ? v : 0.01f * v;
    for (int j = 0; j < PER; ++j) cated[(c * PER + j) * CST + ooff + f] = v;
}

// queries: cated[520+q][ooff+f] = leaky(X[520+q]·W[:,f] + b[f])
__global__ void query_emb_k(const float* __restrict__ X, const float* __restrict__ W,
                            const float* __restrict__ b, float* __restrict__ cated, int ooff) {
    const int q = blockIdx.x, f = threadIdx.x;      // 80 x 128
    const int r = NSUP + q;
    float acc = 0.f;
    for (int k = 0; k < F_IN; ++k) acc += X[r * F_IN + k] * W[k * EMBF + f];
    float v = acc + b[f];
    v = v > 0.f ? v : 0.01f * v;
    cated[r * CST + ooff + f] = v;
}

__global__ void onehot_k(const int* __restrict__ labels, float* __restrict__ cated) {
    const int i = blockIdx.x * blockDim.x + threadIdx.x;
    if (i >= N_NODES) return;
    if (i < NSUP) {
        int l = labels[i];
#pragma unroll
        for (int c = 0; c < C_CLS; ++c) cated[i * CST + FE + c] = (c == l) ? 1.0f : 0.0f;
    } else {
#pragma unroll
        for (int c = 0; c < C_CLS; ++c) cated[i * CST + FE + c] = 0.2f;
    }
}

// csum2[c][k] = sum over class-c rows of cated[r][k], k<261
__global__ void csum_cat_k(const float* __restrict__ cated, float* __restrict__ csum2) {
    const int c = blockIdx.x, k = threadIdx.x;      // 5 x 320 (guarded)
    if (k >= CATD) return;
    float s = 0.f;
    for (int j = 0; j < PER; ++j) s += cated[(c * PER + j) * CST + k];
    csum2[c * CATD + k] = s;
}

// gcn_emb supports -> fc[:, 0:256]
__global__ void supp_fc_k(const float* __restrict__ csum2, const float* __restrict__ Win,
                          const float* __restrict__ bin, float* __restrict__ fc) {
    const int c = blockIdx.x, f = threadIdx.x;      // 5 x 256
    float acc = 0.f;
    for (int k = 0; k < CATD; ++k) acc += csum2[c * CATD + k] * Win[k * FE + f];
    float v = acc * (1.0f / PER) + bin[f];
    v = v > 0.f ? v : 0.01f * v;
    for (int j = 0; j < PER; ++j) fc[(c * PER + j) * FCST + f] = v;
}

// gcn_emb queries -> fc[:, 0:256]
__global__ void query_fc_k(const float* __restrict__ cated, const float* __restrict__ Win,
                           const float* __restrict__ bin, float* __restrict__ fc) {
    const int q = blockIdx.x, f = threadIdx.x;      // 80 x 256
    const int r = NSUP + q;
    float acc = 0.f;
    for (int k = 0; k < CATD; ++k) acc += cated[r * CST + k] * Win[k * FE + f];
    float v = acc + bin[f];
    v = v > 0.f ? v : 0.01f * v;
    fc[r * FCST + f] = v;
}

// hl = cated@Wl+bl ; hr = cated@Wr+br
__global__ __launch_bounds__(256) void mmlr_k(const float* __restrict__ cated,
    const float* __restrict__ Wl, const float* __restrict__ Wr,
    const float* __restrict__ bl, const float* __restrict__ br,
    float* __restrict__ hl, float* __restrict__ hr) {
    __shared__ float xs[CATD];
    const int row = blockIdx.x, t = threadIdx.x;
    xs[t] = cated[row * CST + t];
    if (t < CATD - 256) xs[256 + t] = cated[row * CST + 256 + t];
    __syncthreads();
    float a1 = 0.f, a2 = 0.f;
    for (int k = 0; k < CATD; ++k) {
        float x = xs[k];
        a1 += x * Wl[k * FE + t];
        a2 += x * Wr[k * FE + t];
    }
    hl[row * FE + t] = a1 + bl[t];
    hr[row * FE + t] = a2 + br[t];
}

// GATv2 dst i: dense masked softmax over 600 srcs, weighted sum of hl, elu,
// then fused conv1d(K=3)+sigmoid -> fc[:, 256:510]
__global__ __launch_bounds__(256) void gat_k(const float* __restrict__ hl,
                                             const float* __restrict__ hr,
                                             const float* __restrict__ att,
                                             const float* __restrict__ bgat,
                                             const float* __restrict__ cw,
                                             const float* __restrict__ cb,
                                             float* __restrict__ fc) {
    __shared__ float se[N_NODES];
    __shared__ float red[8];
    __shared__ float go[FE];
    const int i = blockIdx.x, t = threadIdx.x;
    const int lane = t & 63, wave = t >> 6;
    const int ci = (i < NSUP) ? (i / PER) : -1;

    float hri[4], attv[4];
#pragma unroll
    for (int k = 0; k < 4; ++k) {
        hri[k]  = hr[i * FE + lane + 64 * k];
        attv[k] = att[lane + 64 * k];
    }
    for (int j = wave; j < N_NODES; j += 4) {
        bool allowed = (i >= NSUP) || (j >= NSUP) || (j == i) || ((j / PER) != ci);
        float acc = 0.f;
#pragma unroll
        for (int k = 0; k < 4; ++k) {
            float x = hl[j * FE + lane + 64 * k] + hri[k];
            x = x > 0.f ? x : 0.2f * x;
            acc += x * attv[k];
        }
#pragma unroll
        for (int off = 32; off; off >>= 1) acc += __shfl_xor(acc, off);
        if (lane == 0) se[j] = allowed ? acc : -1e30f;
    }
    __syncthreads();
    float m = -1e30f;
    for (int j = t; j < N_NODES; j += 256) m = fmaxf(m, se[j]);
#pragma unroll
    for (int off = 32; off; off >>= 1) m = fmaxf(m, __shfl_xor(m, off));
    if (lane == 0) red[wave] = m;
    __syncthreads();
    m = fmaxf(fmaxf(red[0], red[1]), fmaxf(red[2], red[3]));
    float dsum = 0.f;
    for (int j = t; j < N_NODES; j += 256) dsum += __expf(se[j] - m);
#pragma unroll
    for (int off = 32; off; off >>= 1) dsum += __shfl_xor(dsum, off);
    if (lane == 0) red[4 + wave] = dsum;
    __syncthreads();
    const float inv = 1.f / (red[4] + red[5] + red[6] + red[7]);
    for (int j = t; j < N_NODES; j += 256) se[j] = __expf(se[j] - m) * inv;
    __syncthreads();
    float acc = 0.f;
    for (int j = 0; j < N_NODES; ++j) acc += se[j] * hl[j * FE + t];
    float v = acc + bgat[t];
    v = v > 0.f ? v : (__expf(v) - 1.f);   // elu
    go[t] = v;
    __syncthreads();
    if (t < CONV_OUT) {
        float s = go[t] * cw[0] + go[t + 1] * cw[1] + go[t + 2] * cw[2] + cb[0];
        fc[i * FCST + FE + t] = 1.f / (1.f + __expf(-s));
    }
}

// hlab[600,5] = fc[600,510] @ W_lab[510,5]
__global__ void labmm_k(const float* __restrict__ fc, const float* __restrict__ Wlab,
                        float* __restrict__ hlab) {
    const int idx = blockIdx.x * blockDim.x + threadIdx.x;
    if (idx >= N_NODES * C_CLS) return;
    const int i = idx / C_CLS, c = idx % C_CLS;
    float acc = 0.f;
    for (int k = 0; k < FCD; ++k) acc += fc[i * FCST + k] * Wlab[k * C_CLS + c];
    hlab[idx] = acc;
}

// column sums: sums[0..4] supports, sums[5..9] queries
__global__ void sums_k(const float* __restrict__ hlab, float* __restrict__ sums) {
    const int t = threadIdx.x, lane = t & 63, g = t >> 6;  // g in [0,10)
    const int c = g % C_CLS, seg = g / C_CLS;
    float s = 0.f;
    if (seg == 0) { for (int r = lane; r < NSUP; r += 64) s += hlab[r * C_CLS + c]; }
    else          { for (int r = NSUP + lane; r < N_NODES; r += 64) s += hlab[r * C_CLS + c]; }
#pragma unroll
    for (int off = 32; off; off >>= 1) s += __shfl_xor(s, off);
    if (lane == 0) sums[g] = s;
}

// bipartite pooling + bias -> f32 out
__global__ void final_k(const float* __restrict__ hlab, const float* __restrict__ sums,
                        const float* __restrict__ blab, float* __restrict__ out) {
    const int idx = blockIdx.x * blockDim.x + threadIdx.x;
    if (idx >= N_NODES * C_CLS) return;
    const int i = idx / C_CLS, c = idx % C_CLS;
    const float rs = 1.0f / sqrtf(81.0f * 521.0f);
    float v;
    if (i < NSUP) v = sums[C_CLS + c] * rs + hlab[idx] * (1.0f / 81.0f);
    else          v = sums[c] * rs + hlab[idx] * (1.0f / 521.0f);
    out[idx] = v + blab[c];
}

extern "C" void kernel_launch(void* const* d_in, const int* in_sizes, int n_in,
                              void* d_out, int out_size, void* d_ws, size_t ws_size,
                              hipStream_t stream) {
    (void)in_sizes; (void)n_in; (void)out_size; (void)ws_size;
    const float* f0   = (const float*)d_in[0];
    const float* f1   = (const float*)d_in[1];
    const int* labels = (const int*)d_in[2];
    const float* Wf0  = (const float*)d_in[9];
    const float* bf0  = (const float*)d_in[10];
    const float* Wf1  = (const float*)d_in[11];
    const float* bf1  = (const float*)d_in[12];
    const float* Win  = (const float*)d_in[13];
    const float* bin  = (const float*)d_in[14];
    const float* Wl   = (const float*)d_in[15];
    const float* bl   = (const float*)d_in[16];
    const float* Wr   = (const float*)d_in[17];
    const float* br   = (const float*)d_in[18];
    const float* att  = (const float*)d_in[19];
    const float* bgat = (const float*)d_in[20];
    const float* cw   = (const float*)d_in[21];
    const float* cb   = (const float*)d_in[22];
    const float* Wlab = (const float*)d_in[23];
    const float* blab = (const float*)d_in[24];
    float* out = (float*)d_out;

    float* ws = (float*)d_ws;
    float* cated = ws;             // stride 264
    float* hl    = ws + 160000;
    float* hr    = ws + 313600;
    float* fc    = ws + 467200;    // stride 512
    float* csum  = ws + 774400;    // 5x1024
    float* csum2 = ws + 779520;    // 5x261
    float* hlab  = ws + 780832;    // 600x5
    float* sums  = ws + 783832;    // 10

    csum1024_k<<<dim3(4, 5), 256, 0, stream>>>(f0, csum);
    supp_emb_k<<<5, 128, 0, stream>>>(csum, Wf0, bf0, cated, 0);
    query_emb_k<<<80, 128, 0, stream>>>(f0, Wf0, bf0, cated, 0);
    csum1024_k<<<dim3(4, 5), 256, 0, stream>>>(f1, csum);
    supp_emb_k<<<5, 128, 0, stream>>>(csum, Wf1, bf1, cated, EMBF);
    query_emb_k<<<80, 128, 0, stream>>>(f1, Wf1, bf1, cated, EMBF);
    onehot_k<<<3, 256, 0, stream>>>(labels, cated);
    csum_cat_k<<<5, 320, 0, stream>>>(cated, csum2);
    supp_fc_k<<<5, 256, 0, stream>>>(csum2, Win, bin, fc);
    query_fc_k<<<80, 256, 0, stream>>>(cated, Win, bin, fc);
    mmlr_k<<<600, 256, 0, stream>>>(cated, Wl, Wr, bl, br, hl, hr);
    gat_k<<<600, 256, 0, stream>>>(hl, hr, att, bgat, cw, cb, fc);
    labmm_k<<<12, 256, 0, stream>>>(fc, Wlab, hlab);
    sums_k<<<1, 640, 0, stream>>>(hlab, sums);
    final_k<<<12, 256, 0, stream>>>(hlab, sums, blab, out);
}

// Round 5
// 101.386 us; speedup vs baseline: 2.9072x; 2.9072x over previous
//
#include <hip/hip_runtime.h>

#define N_NODES 600
#define NSUP    520
#define NQ      80
#define C_CLS   5
#define PER     104
#define F_IN    1024
#define EMBF    128
#define FE      256
#define CATD    261
#define CST     264   // padded stride of cated85
#define FCD     510
#define FCST    512
#define CONV_OUT 254  // FE - K + 1
#define R85     85    // 5 class reps + 80 queries
#define EST     96    // padded stride of E85

// K1: partial class sums of features. grid (4 kchunks, 5 classes, 8=set*4+jseg), block 256.
// csump[set][js][c][k] = sum of 26 class-c rows
__global__ void csum_k(const float* __restrict__ f0, const float* __restrict__ f1,
                       float* __restrict__ csump) {
    const int k = blockIdx.x * 256 + threadIdx.x;
    const int c = blockIdx.y;
    const int z = blockIdx.z, set = z >> 2, js = z & 3;
    const float* X = set ? f1 : f0;
    const int r0 = c * PER + js * 26;
    float s = 0.f;
    for (int j = 0; j < 26; ++j) s += X[(r0 + j) * F_IN + k];
    csump[((set * 4 + js) * C_CLS + c) * F_IN + k] = s;
}

// K2: partial embedding matmul over k-chunks. grid (5 rowtiles of 17, 2 sets, 8 kchunks), block 128.
// part[set][kc][r85][f] = sum_{k in chunk} x[r85][k] * W[k][f]
__global__ __launch_bounds__(128) void emb_k(const float* __restrict__ f0,
                                             const float* __restrict__ f1,
                                             const float* __restrict__ csump,
                                             const float* __restrict__ Wf0,
                                             const float* __restrict__ Wf1,
                                             float* __restrict__ part) {
    __shared__ float xs[17 * 128];
    const int f = threadIdx.x;
    const int tile = blockIdx.x, set = blockIdx.y, kc = blockIdx.z;
    const float* X = set ? f1 : f0;
    const float* W = set ? Wf1 : Wf0;
    const int k0 = kc * 128;
    for (int e = f; e < 17 * 128; e += 128) {
        const int rl = e >> 7, kk = e & 127;
        const int r85 = tile * 17 + rl;
        float v;
        if (r85 < C_CLS) {
            v = csump[((set * 4 + 0) * C_CLS + r85) * F_IN + k0 + kk]
              + csump[((set * 4 + 1) * C_CLS + r85) * F_IN + k0 + kk]
              + csump[((set * 4 + 2) * C_CLS + r85) * F_IN + k0 + kk]
              + csump[((set * 4 + 3) * C_CLS + r85) * F_IN + k0 + kk];
        } else {
            v = X[(NSUP + r85 - C_CLS) * F_IN + k0 + kk];
        }
        xs[e] = v;
    }
    __syncthreads();
    float acc[17];
#pragma unroll
    for (int rl = 0; rl < 17; ++rl) acc[rl] = 0.f;
    for (int kk = 0; kk < 128; ++kk) {
        const float w = W[(k0 + kk) * EMBF + f];
#pragma unroll
        for (int rl = 0; rl < 17; ++rl) acc[rl] += xs[rl * 128 + kk] * w;
    }
#pragma unroll
    for (int rl = 0; rl < 17; ++rl)
        part[((set * 8 + kc) * R85 + tile * 17 + rl) * EMBF + f] = acc[rl];
}

// K3: reduce partials + scale/bias/leaky + onehot -> cated85[85][264]. grid 85, block 256.
__global__ void embfin_k(const float* __restrict__ part, const float* __restrict__ bf0,
                         const float* __restrict__ bf1, float* __restrict__ cated85) {
    const int r = blockIdx.x, t = threadIdx.x;
    const int set = t >> 7, f = t & 127;
    float s = 0.f;
#pragma unroll
    for (int kc = 0; kc < 8; ++kc) s += part[((set * 8 + kc) * R85 + r) * EMBF + f];
    if (r < C_CLS) s *= (1.0f / PER);    // class rep used SUM of 104 rows; GCN norm = 1/104
    s += (set ? bf1[f] : bf0[f]);
    s = s > 0.f ? s : 0.01f * s;
    cated85[r * CST + t] = s;
    if (t < C_CLS) cated85[r * CST + FE + t] = (r < C_CLS) ? (t == r ? 1.f : 0.f) : 0.2f;
}

// K4: three matmuls off cated85. grid (17 rowtiles of 5, 3 mats), block 256.
// mat0: fc85[:,0:256] = leaky(cated85@Win + bin); mat1: hl85 = @Wl+bl; mat2: hr85 = @Wr+br
__global__ __launch_bounds__(256) void mm3_85_k(const float* __restrict__ cated85,
    const float* __restrict__ Win, const float* __restrict__ bin,
    const float* __restrict__ Wl,  const float* __restrict__ bl,
    const float* __restrict__ Wr,  const float* __restrict__ br,
    float* __restrict__ fc85, float* __restrict__ hl85, float* __restrict__ hr85) {
    __shared__ float xs[5 * CATD];
    const int t = threadIdx.x;
    const int r0 = blockIdx.x * 5;
    const int mat = blockIdx.y;
    const float* W = (mat == 0) ? Win : (mat == 1 ? Wl : Wr);
    const float* B = (mat == 0) ? bin : (mat == 1 ? bl : br);
    for (int e = t; e < 5 * CATD; e += 256) {
        const int rl = e / CATD, k = e - rl * CATD;
        xs[e] = cated85[(r0 + rl) * CST + k];
    }
    __syncthreads();
    float acc[5] = {0.f, 0.f, 0.f, 0.f, 0.f};
    for (int k = 0; k < CATD; ++k) {
        const float w = W[k * FE + t];
#pragma unroll
        for (int rl = 0; rl < 5; ++rl) acc[rl] += xs[rl * CATD + k] * w;
    }
    const float b = B[t];
#pragma unroll
    for (int rl = 0; rl < 5; ++rl) {
        const int r = r0 + rl;
        float v = acc[rl] + b;
        if (mat == 0) { v = v > 0.f ? v : 0.01f * v; fc85[r * FCST + t] = v; }
        else if (mat == 1) hl85[r * FE + t] = v;
        else               hr85[r * FE + t] = v;
    }
}

// K5: E85[ir][jr] = att . leaky(hl85[jr] + hr85[ir]). grid 85, block 256 (4 waves).
__global__ void e85_k(const float* __restrict__ hl85, const float* __restrict__ hr85,
                      const float* __restrict__ att, float* __restrict__ E85) {
    const int ir = blockIdx.x, t = threadIdx.x;
    const int lane = t & 63, w = t >> 6;
    float hrv[4], av[4];
#pragma unroll
    for (int p = 0; p < 4; ++p) {
        hrv[p] = hr85[ir * FE + p * 64 + lane];
        av[p]  = att[p * 64 + lane];
    }
    for (int jr = w; jr < R85; jr += 4) {
        float s = 0.f;
#pragma unroll
        for (int p = 0; p < 4; ++p) {
            float x = hl85[jr * FE + p * 64 + lane] + hrv[p];
            x = x > 0.f ? x : 0.2f * x;
            s += x * av[p];
        }
#pragma unroll
        for (int off = 32; off; off >>= 1) s += __shfl_xor(s, off);
        if (lane == 0) E85[ir * EST + jr] = s;
    }
}

// K6: per rep-row softmax (with multiplicities) + aggregate + elu + conv1d + sigmoid.
// grid 85, block 256. Writes fc85[:, 256:510].
__global__ __launch_bounds__(256) void gatagg_k(const float* __restrict__ E85,
                                                const float* __restrict__ hl85,
                                                const float* __restrict__ bgat,
                                                const float* __restrict__ cw,
                                                const float* __restrict__ cb,
                                                float* __restrict__ fc85) {
    __shared__ float es[R85], wsm[R85], go[FE], red[2];
    const int ir = blockIdx.x, t = threadIdx.x;
    if (t < R85) es[t] = E85[ir * EST + t];
    __syncthreads();
    if (t == 0) {
        float m = es[0];
        for (int j = 1; j < R85; ++j) m = fmaxf(m, es[j]);
        red[0] = m;
    }
    __syncthreads();
    const float m = red[0];
    if (t < R85) {
        // multiplicity: support dst (ir<5): own class only via self-loop (1), others 104.
        // query dst: all supports (104 per class), all queries (1 each incl. self).
        float n;
        if (ir < C_CLS) n = (t < C_CLS) ? (t == ir ? 1.f : 104.f) : 1.f;
        else            n = (t < C_CLS) ? 104.f : 1.f;
        wsm[t] = n * __expf(es[t] - m);
    }
    __syncthreads();
    if (t == 0) {
        float d = 0.f;
        for (int j = 0; j < R85; ++j) d += wsm[j];
        red[1] = 1.f / d;
    }
    __syncthreads();
    const float inv = red[1];
    float acc = 0.f;
    for (int jr = 0; jr < R85; ++jr) acc += wsm[jr] * hl85[jr * FE + t];
    float v = acc * inv + bgat[t];
    v = v > 0.f ? v : (__expf(v) - 1.f);   // elu
    go[t] = v;
    __syncthreads();
    if (t < CONV_OUT) {
        float s = go[t] * cw[0] + go[t + 1] * cw[1] + go[t + 2] * cw[2] + cb[0];
        fc85[ir * FCST + FE + t] = 1.f / (1.f + __expf(-s));
    }
}

// K7: label matmul on 85 rows + bipartite pooling broadcast to 600x5. grid 1, block 512.
__global__ __launch_bounds__(512) void final85_k(const float* __restrict__ fc85,
                                                 const float* __restrict__ Wlab,
                                                 const float* __restrict__ blab,
                                                 float* __restrict__ out) {
    __shared__ float hlab[R85][C_CLS];
    __shared__ float sS[C_CLS], sQ[C_CLS];
    const int t = threadIdx.x, lane = t & 63, w = t >> 6;  // 8 waves
    for (int r = w; r < R85; r += 8) {
        float a[C_CLS] = {0.f, 0.f, 0.f, 0.f, 0.f};
        for (int k = lane; k < FCD; k += 64) {
            const float x = fc85[r * FCST + k];
#pragma unroll
            for (int c = 0; c < C_CLS; ++c) a[c] += x * Wlab[k * C_CLS + c];
        }
#pragma unroll
        for (int c = 0; c < C_CLS; ++c) {
#pragma unroll
            for (int off = 32; off; off >>= 1) a[c] += __shfl_xor(a[c], off);
        }
        if (lane == 0) {
#pragma unroll
            for (int c = 0; c < C_CLS; ++c) hlab[r][c] = a[c];
        }
    }
    __syncthreads();
    if (t < C_CLS) {
        float s = 0.f;
        for (int cl = 0; cl < C_CLS; ++cl) s += hlab[cl][t];
        sS[t] = 104.f * s;                       // sum over 520 support rows
    } else if (t < 2 * C_CLS) {
        const int c = t - C_CLS;
        float s = 0.f;
        for (int q = 0; q < NQ; ++q) s += hlab[C_CLS + q][c];
        sQ[c] = s;                               // sum over 80 query rows
    }
    __syncthreads();
    const float rs = rsqrtf(81.f * 521.f);
    for (int idx = t; idx < N_NODES * C_CLS; idx += 512) {
        const int i = idx / C_CLS, c = idx - i * C_CLS;
        float v;
        if (i < NSUP) v = sQ[c] * rs + hlab[i / PER][c] * (1.0f / 81.0f);
        else          v = sS[c] * rs + hlab[C_CLS + i - NSUP][c] * (1.0f / 521.0f);
        out[idx] = v + blab[c];
    }
}

extern "C" void kernel_launch(void* const* d_in, const int* in_sizes, int n_in,
                              void* d_out, int out_size, void* d_ws, size_t ws_size,
                              hipStream_t stream) {
    (void)in_sizes; (void)n_in; (void)out_size; (void)ws_size;
    const float* f0   = (const float*)d_in[0];
    const float* f1   = (const float*)d_in[1];
    const float* Wf0  = (const float*)d_in[9];
    const float* bf0  = (const float*)d_in[10];
    const float* Wf1  = (const float*)d_in[11];
    const float* bf1  = (const float*)d_in[12];
    const float* Win  = (const float*)d_in[13];
    const float* bin  = (const float*)d_in[14];
    const float* Wl   = (const float*)d_in[15];
    const float* bl   = (const float*)d_in[16];
    const float* Wr   = (const float*)d_in[17];
    const float* br   = (const float*)d_in[18];
    const float* att  = (const float*)d_in[19];
    const float* bgat = (const float*)d_in[20];
    const float* cw   = (const float*)d_in[21];
    const float* cb   = (const float*)d_in[22];
    const float* Wlab = (const float*)d_in[23];
    const float* blab = (const float*)d_in[24];
    float* out = (float*)d_out;

    float* ws = (float*)d_ws;
    float* csump   = ws;            // [2][4][5][1024] = 40960
    float* part    = ws + 40960;    // [2][8][85][128] = 174080 -> 215040
    float* cated85 = ws + 215040;   // [85][264] = 22440 -> 237480
    float* fc85    = ws + 237504;   // [85][512] = 43520 -> 281024
    float* hl85    = ws + 281024;   // [85][256] = 21760 -> 302784
    float* hr85    = ws + 302784;   // [85][256] = 21760 -> 324544
    float* E85     = ws + 324544;   // [85][96]  = 8160  -> 332704 (~1.33 MB)

    csum_k   <<<dim3(4, 5, 8), 256, 0, stream>>>(f0, f1, csump);
    emb_k    <<<dim3(5, 2, 8), 128, 0, stream>>>(f0, f1, csump, Wf0, Wf1, part);
    embfin_k <<<85, 256, 0, stream>>>(part, bf0, bf1, cated85);
    mm3_85_k <<<dim3(17, 3), 256, 0, stream>>>(cated85, Win, bin, Wl, bl, Wr, br,
                                               fc85, hl85, hr85);
    e85_k    <<<85, 256, 0, stream>>>(hl85, hr85, att, E85);
    gatagg_k <<<85, 256, 0, stream>>>(E85, hl85, bgat, cw, cb, fc85);
    final85_k<<<1, 512, 0, stream>>>(fc85, Wlab, blab, out);
}

// Round 6
// 83.618 us; speedup vs baseline: 3.5249x; 1.2125x over previous
//
#include <hip/hip_runtime.h>

#define N_NODES 600
#define NSUP    520
#define NQ      80
#define C_CLS   5
#define PER     104
#define F_IN    1024
#define EMBF    128
#define FE      256
#define CATD    261
#define CST     264   // padded stride of cated85
#define FCD     510
#define FCST    512
#define CONV_OUT 254  // FE - K + 1
#define R85     85    // 5 class reps + 80 queries

// K1: partial class sums of features. grid (4 kchunks, 5 classes, 8=set*4+jseg), block 256.
// csump[set*4+js][c][k] = sum of 26 class-c rows
__global__ void csum_k(const float* __restrict__ f0, const float* __restrict__ f1,
                       float* __restrict__ csump) {
    const int k = blockIdx.x * 256 + threadIdx.x;
    const int c = blockIdx.y;
    const int z = blockIdx.z, set = z >> 2, js = z & 3;
    const float* X = set ? f1 : f0;
    const int r0 = c * PER + js * 26;
    float s = 0.f;
#pragma unroll 13
    for (int j = 0; j < 26; ++j) s += X[(r0 + j) * F_IN + k];
    csump[((set * 4 + js) * C_CLS + c) * F_IN + k] = s;
}

// K2: fused embedding matmul + bias/leaky/onehot -> cated85[85][264].
// grid (85 rows, 2 sets), block 512: f = t&127, kseg = t>>7 (4 segs of 256 k).
__global__ __launch_bounds__(512) void emb_k(const float* __restrict__ f0,
                                             const float* __restrict__ f1,
                                             const float* __restrict__ csump,
                                             const float* __restrict__ Wf0,
                                             const float* __restrict__ Wf1,
                                             const float* __restrict__ bf0,
                                             const float* __restrict__ bf1,
                                             float* __restrict__ cated85) {
    __shared__ float xs[F_IN];
    __shared__ float part[512];
    const int r = blockIdx.x, set = blockIdx.y;
    const int t = threadIdx.x;
    const float* X = set ? f1 : f0;
    const float* W = set ? Wf1 : Wf0;
    if (t < 256) {
        float4 v;
        if (r < C_CLS) {
            const float4* c0 = (const float4*)(csump + ((set * 4 + 0) * C_CLS + r) * F_IN);
            const float4* c1 = (const float4*)(csump + ((set * 4 + 1) * C_CLS + r) * F_IN);
            const float4* c2 = (const float4*)(csump + ((set * 4 + 2) * C_CLS + r) * F_IN);
            const float4* c3 = (const float4*)(csump + ((set * 4 + 3) * C_CLS + r) * F_IN);
            float4 a = c0[t], b = c1[t], c = c2[t], d = c3[t];
            v.x = a.x + b.x + c.x + d.x;
            v.y = a.y + b.y + c.y + d.y;
            v.z = a.z + b.z + c.z + d.z;
            v.w = a.w + b.w + c.w + d.w;
        } else {
            v = ((const float4*)(X + (size_t)(NSUP + r - C_CLS) * F_IN))[t];
        }
        ((float4*)xs)[t] = v;
    }
    __syncthreads();
    const int f = t & 127, kseg = t >> 7;
    const float* Wp = W + (size_t)(kseg * 256) * EMBF + f;
    const float* xp = xs + kseg * 256;
    float acc = 0.f;
#pragma unroll 16
    for (int k = 0; k < 256; ++k) acc += xp[k] * Wp[k * EMBF];
    part[t] = acc;
    __syncthreads();
    if (t < 128) {
        float s = part[t] + part[t + 128] + part[t + 256] + part[t + 384];
        if (r < C_CLS) s *= (1.0f / PER);       // class rep = mean of 104 rows
        s += (set ? bf1[t] : bf0[t]);
        s = s > 0.f ? s : 0.01f * s;
        cated85[r * CST + set * EMBF + t] = s;
    }
    if (set == 0 && t < C_CLS)
        cated85[r * CST + FE + t] = (r < C_CLS) ? (t == r ? 1.f : 0.f) : 0.2f;
}

// K3: three matmuls off cated85. grid (17 rowtiles of 5, 3 mats), block 256.
__global__ __launch_bounds__(256) void mm3_85_k(const float* __restrict__ cated85,
    const float* __restrict__ Win, const float* __restrict__ bin,
    const float* __restrict__ Wl,  const float* __restrict__ bl,
    const float* __restrict__ Wr,  const float* __restrict__ br,
    float* __restrict__ fc85, float* __restrict__ hl85, float* __restrict__ hr85) {
    __shared__ float xs[5 * CATD];
    const int t = threadIdx.x;
    const int r0 = blockIdx.x * 5;
    const int mat = blockIdx.y;
    const float* W = (mat == 0) ? Win : (mat == 1 ? Wl : Wr);
    const float* B = (mat == 0) ? bin : (mat == 1 ? bl : br);
    for (int e = t; e < 5 * CATD; e += 256) {
        const int rl = e / CATD, k = e - rl * CATD;
        xs[e] = cated85[(r0 + rl) * CST + k];
    }
    __syncthreads();
    float acc[5] = {0.f, 0.f, 0.f, 0.f, 0.f};
#pragma unroll 4
    for (int k = 0; k < CATD; ++k) {
        const float w = W[k * FE + t];
#pragma unroll
        for (int rl = 0; rl < 5; ++rl) acc[rl] += xs[rl * CATD + k] * w;
    }
    const float b = B[t];
#pragma unroll
    for (int rl = 0; rl < 5; ++rl) {
        const int r = r0 + rl;
        float v = acc[rl] + b;
        if (mat == 0) { v = v > 0.f ? v : 0.01f * v; fc85[r * FCST + t] = v; }
        else if (mat == 1) hl85[r * FE + t] = v;
        else               hr85[r * FE + t] = v;
    }
}

// K4: fused GATv2 row: E-row + softmax(multiplicities) + aggregate + elu + conv + sigmoid.
// grid 85, block 256 (4 waves). hl85 staged in LDS (87 KB).
__global__ __launch_bounds__(256) void gat_k(const float* __restrict__ hl85,
                                             const float* __restrict__ hr85,
                                             const float* __restrict__ att,
                                             const float* __restrict__ bgat,
                                             const float* __restrict__ cw,
                                             const float* __restrict__ cb,
                                             float* __restrict__ fc85) {
    __shared__ float hls[R85 * FE];
    __shared__ float es[R85 + 3], wsm[R85 + 3], go[FE], red[2];
    const int ir = blockIdx.x, t = threadIdx.x;
    const int lane = t & 63, w = t >> 6;

    for (int e = t; e < R85 * FE / 4; e += 256)
        ((float4*)hls)[e] = ((const float4*)hl85)[e];
    float hrv[4], av[4];
#pragma unroll
    for (int p = 0; p < 4; ++p) {
        hrv[p] = hr85[ir * FE + p * 64 + lane];
        av[p]  = att[p * 64 + lane];
    }
    __syncthreads();
    for (int jr = w; jr < R85; jr += 4) {
        float s = 0.f;
#pragma unroll
        for (int p = 0; p < 4; ++p) {
            float x = hls[jr * FE + p * 64 + lane] + hrv[p];
            x = x > 0.f ? x : 0.2f * x;
            s += x * av[p];
        }
#pragma unroll
        for (int off = 32; off; off >>= 1) s += __shfl_xor(s, off);
        if (lane == 0) es[jr] = s;
    }
    __syncthreads();
    if (t == 0) {
        float m = es[0];
        for (int j = 1; j < R85; ++j) m = fmaxf(m, es[j]);
        red[0] = m;
    }
    __syncthreads();
    const float m = red[0];
    if (t < R85) {
        // multiplicity: support dst ir<5: own class 1 (self-loop only), other classes 104,
        // queries 1. query dst: classes 104, queries 1 (incl. self-loop).
        float n;
        if (ir < C_CLS) n = (t < C_CLS) ? (t == ir ? 1.f : 104.f) : 1.f;
        else            n = (t < C_CLS) ? 104.f : 1.f;
        wsm[t] = n * __expf(es[t] - m);
    }
    __syncthreads();
    if (t == 0) {
        float d = 0.f;
        for (int j = 0; j < R85; ++j) d += wsm[j];
        red[1] = 1.f / d;
    }
    __syncthreads();
    const float inv = red[1];
    float acc = 0.f;
#pragma unroll 5
    for (int jr = 0; jr < R85; ++jr) acc += wsm[jr] * hls[jr * FE + t];
    float v = acc * inv + bgat[t];
    v = v > 0.f ? v : (__expf(v) - 1.f);   // elu
    go[t] = v;
    __syncthreads();
    if (t < CONV_OUT) {
        float s = go[t] * cw[0] + go[t + 1] * cw[1] + go[t + 2] * cw[2] + cb[0];
        fc85[ir * FCST + FE + t] = 1.f / (1.f + __expf(-s));
    }
}

// K5: label matmul on 85 rows + bipartite pooling broadcast to 600x5. grid 1, block 512.
__global__ __launch_bounds__(512) void final85_k(const float* __restrict__ fc85,
                                                 const float* __restrict__ Wlab,
                                                 const float* __restrict__ blab,
                                                 float* __restrict__ out) {
    __shared__ float hlab[R85][C_CLS];
    __shared__ float sS[C_CLS], sQ[C_CLS];
    const int t = threadIdx.x, lane = t & 63, w = t >> 6;  // 8 waves
    for (int r = w; r < R85; r += 8) {
        float a[C_CLS] = {0.f, 0.f, 0.f, 0.f, 0.f};
        for (int k = lane; k < FCD; k += 64) {
            const float x = fc85[r * FCST + k];
#pragma unroll
            for (int c = 0; c < C_CLS; ++c) a[c] += x * Wlab[k * C_CLS + c];
        }
#pragma unroll
        for (int c = 0; c < C_CLS; ++c) {
#pragma unroll
            for (int off = 32; off; off >>= 1) a[c] += __shfl_xor(a[c], off);
        }
        if (lane == 0) {
#pragma unroll
            for (int c = 0; c < C_CLS; ++c) hlab[r][c] = a[c];
        }
    }
    __syncthreads();
    if (t < C_CLS) {
        float s = 0.f;
        for (int cl = 0; cl < C_CLS; ++cl) s += hlab[cl][t];
        sS[t] = 104.f * s;                       // sum over 520 support rows
    } else if (t < 2 * C_CLS) {
        const int c = t - C_CLS;
        float s = 0.f;
        for (int q = 0; q < NQ; ++q) s += hlab[C_CLS + q][c];
        sQ[c] = s;                               // sum over 80 query rows
    }
    __syncthreads();
    const float rs = rsqrtf(81.f * 521.f);
    for (int idx = t; idx < N_NODES * C_CLS; idx += 512) {
        const int i = idx / C_CLS, c = idx - i * C_CLS;
        float v;
        if (i < NSUP) v = sQ[c] * rs + hlab[i / PER][c] * (1.0f / 81.0f);
        else          v = sS[c] * rs + hlab[C_CLS + i - NSUP][c] * (1.0f / 521.0f);
        out[idx] = v + blab[c];
    }
}

extern "C" void kernel_launch(void* const* d_in, const int* in_sizes, int n_in,
                              void* d_out, int out_size, void* d_ws, size_t ws_size,
                              hipStream_t stream) {
    (void)in_sizes; (void)n_in; (void)out_size; (void)ws_size;
    const float* f0   = (const float*)d_in[0];
    const float* f1   = (const float*)d_in[1];
    const float* Wf0  = (const float*)d_in[9];
    const float* bf0  = (const float*)d_in[10];
    const float* Wf1  = (const float*)d_in[11];
    const float* bf1  = (const float*)d_in[12];
    const float* Win  = (const float*)d_in[13];
    const float* bin  = (const float*)d_in[14];
    const float* Wl   = (const float*)d_in[15];
    const float* bl   = (const float*)d_in[16];
    const float* Wr   = (const float*)d_in[17];
    const float* br   = (const float*)d_in[18];
    const float* att  = (const float*)d_in[19];
    const float* bgat = (const float*)d_in[20];
    const float* cw   = (const float*)d_in[21];
    const float* cb   = (const float*)d_in[22];
    const float* Wlab = (const float*)d_in[23];
    const float* blab = (const float*)d_in[24];
    float* out = (float*)d_out;

    float* ws = (float*)d_ws;
    float* csump   = ws;            // [8][5][1024] = 40960
    float* cated85 = ws + 40960;    // [85][264] = 22440
    float* fc85    = ws + 63424;    // [85][512] = 43520
    float* hl85    = ws + 106944;   // [85][256] = 21760
    float* hr85    = ws + 128704;   // [85][256] = 21760 -> 150464 (~0.6 MB)

    csum_k   <<<dim3(4, 5, 8), 256, 0, stream>>>(f0, f1, csump);
    emb_k    <<<dim3(85, 2), 512, 0, stream>>>(f0, f1, csump, Wf0, Wf1, bf0, bf1, cated85);
    mm3_85_k <<<dim3(17, 3), 256, 0, stream>>>(cated85, Win, bin, Wl, bl, Wr, br,
                                               fc85, hl85, hr85);
    gat_k    <<<85, 256, 0, stream>>>(hl85, hr85, att, bgat, cw, cb, fc85);
    final85_k<<<1, 512, 0, stream>>>(fc85, Wlab, blab, out);
}

// Round 7
// 74.557 us; speedup vs baseline: 3.9533x; 1.1215x over previous
//
#include <hip/hip_runtime.h>

#define N_NODES 600
#define NSUP    520
#define NQ      80
#define C_CLS   5
#define PER     104
#define F_IN    1024
#define EMBF    128
#define FE      256
#define CATD    261
#define CST     264   // padded stride of cated85
#define FCD     510
#define FCST    512
#define CONV_OUT 254  // FE - K + 1
#define R85     85    // 5 class reps + 80 queries

// K1: partial class sums of features. grid (4 kchunks, 5 classes, 8=set*4+jseg), block 256.
__global__ void csum_k(const float* __restrict__ f0, const float* __restrict__ f1,
                       float* __restrict__ csump) {
    const int k = blockIdx.x * 256 + threadIdx.x;
    const int c = blockIdx.y;
    const int z = blockIdx.z, set = z >> 2, js = z & 3;
    const float* X = set ? f1 : f0;
    const int r0 = c * PER + js * 26;
    float s = 0.f;
#pragma unroll 13
    for (int j = 0; j < 26; ++j) s += X[(r0 + j) * F_IN + k];
    csump[((set * 4 + js) * C_CLS + c) * F_IN + k] = s;
}

// K2: fused embedding matmul + bias/leaky/onehot -> cated85[85][264].
// grid (85 rows, 2 sets), block 512: f = t&127, kseg = t>>7.
__global__ __launch_bounds__(512) void emb_k(const float* __restrict__ f0,
                                             const float* __restrict__ f1,
                                             const float* __restrict__ csump,
                                             const float* __restrict__ Wf0,
                                             const float* __restrict__ Wf1,
                                             const float* __restrict__ bf0,
                                             const float* __restrict__ bf1,
                                             float* __restrict__ cated85) {
    __shared__ float xs[F_IN];
    __shared__ float part[512];
    const int r = blockIdx.x, set = blockIdx.y;
    const int t = threadIdx.x;
    const float* X = set ? f1 : f0;
    const float* W = set ? Wf1 : Wf0;
    if (t < 256) {
        float4 v;
        if (r < C_CLS) {
            const float4* c0 = (const float4*)(csump + ((set * 4 + 0) * C_CLS + r) * F_IN);
            const float4* c1 = (const float4*)(csump + ((set * 4 + 1) * C_CLS + r) * F_IN);
            const float4* c2 = (const float4*)(csump + ((set * 4 + 2) * C_CLS + r) * F_IN);
            const float4* c3 = (const float4*)(csump + ((set * 4 + 3) * C_CLS + r) * F_IN);
            float4 a = c0[t], b = c1[t], c = c2[t], d = c3[t];
            v.x = a.x + b.x + c.x + d.x;
            v.y = a.y + b.y + c.y + d.y;
            v.z = a.z + b.z + c.z + d.z;
            v.w = a.w + b.w + c.w + d.w;
        } else {
            v = ((const float4*)(X + (size_t)(NSUP + r - C_CLS) * F_IN))[t];
        }
        ((float4*)xs)[t] = v;
    }
    __syncthreads();
    const int f = t & 127, kseg = t >> 7;
    const float* Wp = W + (size_t)(kseg * 256) * EMBF + f;
    const float* xp = xs + kseg * 256;
    float acc = 0.f;
#pragma unroll 16
    for (int k = 0; k < 256; ++k) acc += xp[k] * Wp[k * EMBF];
    part[t] = acc;
    __syncthreads();
    if (t < 128) {
        float s = part[t] + part[t + 128] + part[t + 256] + part[t + 384];
        if (r < C_CLS) s *= (1.0f / PER);       // class rep = mean of 104 rows
        s += (set ? bf1[t] : bf0[t]);
        s = s > 0.f ? s : 0.01f * s;
        cated85[r * CST + set * EMBF + t] = s;
    }
    if (set == 0 && t < C_CLS)
        cated85[r * CST + FE + t] = (r < C_CLS) ? (t == r ? 1.f : 0.f) : 0.2f;
}

// K3: three matmuls off cated85. grid (85 rows, 3 mats), block 256.
// Single accumulator per thread + deep unroll => 16 W-loads in flight (emb_k pattern).
__global__ __launch_bounds__(256) void mm3_85_k(const float* __restrict__ cated85,
    const float* __restrict__ Win, const float* __restrict__ bin,
    const float* __restrict__ Wl,  const float* __restrict__ bl,
    const float* __restrict__ Wr,  const float* __restrict__ br,
    float* __restrict__ fc85, float* __restrict__ hl85, float* __restrict__ hr85) {
    __shared__ float xs[CATD + 3];
    const int t = threadIdx.x;
    const int r = blockIdx.x;       // 85
    const int mat = blockIdx.y;     // 3
    const float* W = (mat == 0) ? Win : (mat == 1 ? Wl : Wr);
    const float* B = (mat == 0) ? bin : (mat == 1 ? bl : br);
    if (t < CATD) xs[t] = cated85[r * CST + t];
    if (t < CATD - 256) xs[256 + t] = cated85[r * CST + 256 + t];
    __syncthreads();
    const float* Wp = W + t;
    float acc = 0.f;
#pragma unroll 16
    for (int k = 0; k < CATD; ++k) acc += xs[k] * Wp[(size_t)k * FE];
    float v = acc + B[t];
    if (mat == 0) { v = v > 0.f ? v : 0.01f * v; fc85[r * FCST + t] = v; }
    else if (mat == 1) hl85[r * FE + t] = v;
    else               hr85[r * FE + t] = v;
}

// K4: fused GATv2 row: E-row + softmax(multiplicities) + aggregate + elu + conv + sigmoid.
// grid 85, block 256 (4 waves). hl85 staged in LDS (87 KB).
__global__ __launch_bounds__(256) void gat_k(const float* __restrict__ hl85,
                                             const float* __restrict__ hr85,
                                             const float* __restrict__ att,
                                             const float* __restrict__ bgat,
                                             const float* __restrict__ cw,
                                             const float* __restrict__ cb,
                                             float* __restrict__ fc85) {
    __shared__ float hls[R85 * FE];
    __shared__ float es[R85 + 3], wsm[R85 + 3], go[FE], red[2];
    const int ir = blockIdx.x, t = threadIdx.x;
    const int lane = t & 63, w = t >> 6;

    for (int e = t; e < R85 * FE / 4; e += 256)
        ((float4*)hls)[e] = ((const float4*)hl85)[e];
    float hrv[4], av[4];
#pragma unroll
    for (int p = 0; p < 4; ++p) {
        hrv[p] = hr85[ir * FE + p * 64 + lane];
        av[p]  = att[p * 64 + lane];
    }
    __syncthreads();
    for (int jr = w; jr < R85; jr += 4) {
        float s = 0.f;
#pragma unroll
        for (int p = 0; p < 4; ++p) {
            float x = hls[jr * FE + p * 64 + lane] + hrv[p];
            x = x > 0.f ? x : 0.2f * x;
            s += x * av[p];
        }
#pragma unroll
        for (int off = 32; off; off >>= 1) s += __shfl_xor(s, off);
        if (lane == 0) es[jr] = s;
    }
    __syncthreads();
    if (t == 0) {
        float m = es[0];
        for (int j = 1; j < R85; ++j) m = fmaxf(m, es[j]);
        red[0] = m;
    }
    __syncthreads();
    const float m = red[0];
    if (t < R85) {
        // multiplicity: support dst ir<5: own class 1 (self-loop), other classes 104, queries 1.
        // query dst: classes 104, queries 1 (incl. self-loop).
        float n;
        if (ir < C_CLS) n = (t < C_CLS) ? (t == ir ? 1.f : 104.f) : 1.f;
        else            n = (t < C_CLS) ? 104.f : 1.f;
        wsm[t] = n * __expf(es[t] - m);
    }
    __syncthreads();
    if (t == 0) {
        float d = 0.f;
        for (int j = 0; j < R85; ++j) d += wsm[j];
        red[1] = 1.f / d;
    }
    __syncthreads();
    const float inv = red[1];
    float acc = 0.f;
#pragma unroll 5
    for (int jr = 0; jr < R85; ++jr) acc += wsm[jr] * hls[jr * FE + t];
    float v = acc * inv + bgat[t];
    v = v > 0.f ? v : (__expf(v) - 1.f);   // elu
    go[t] = v;
    __syncthreads();
    if (t < CONV_OUT) {
        float s = go[t] * cw[0] + go[t + 1] * cw[1] + go[t + 2] * cw[2] + cb[0];
        fc85[ir * FCST + FE + t] = 1.f / (1.f + __expf(-s));
    }
}

// K5: label matmul on 85 rows + bipartite pooling broadcast to 600x5. grid 1, block 512.
__global__ __launch_bounds__(512) void final85_k(const float* __restrict__ fc85,
                                                 const float* __restrict__ Wlab,
                                                 const float* __restrict__ blab,
                                                 float* __restrict__ out) {
    __shared__ float hlab[R85][C_CLS];
    __shared__ float sS[C_CLS], sQ[C_CLS];
    const int t = threadIdx.x, lane = t & 63, w = t >> 6;  // 8 waves
    for (int r = w; r < R85; r += 8) {
        float a[C_CLS] = {0.f, 0.f, 0.f, 0.f, 0.f};
        for (int k = lane; k < FCD; k += 64) {
            const float x = fc85[r * FCST + k];
#pragma unroll
            for (int c = 0; c < C_CLS; ++c) a[c] += x * Wlab[k * C_CLS + c];
        }
#pragma unroll
        for (int c = 0; c < C_CLS; ++c) {
#pragma unroll
            for (int off = 32; off; off >>= 1) a[c] += __shfl_xor(a[c], off);
        }
        if (lane == 0) {
#pragma unroll
            for (int c = 0; c < C_CLS; ++c) hlab[r][c] = a[c];
        }
    }
    __syncthreads();
    if (t < C_CLS) {
        float s = 0.f;
        for (int cl = 0; cl < C_CLS; ++cl) s += hlab[cl][t];
        sS[t] = 104.f * s;                       // sum over 520 support rows
    } else if (t < 2 * C_CLS) {
        const int c = t - C_CLS;
        float s = 0.f;
        for (int q = 0; q < NQ; ++q) s += hlab[C_CLS + q][c];
        sQ[c] = s;                               // sum over 80 query rows
    }
    __syncthreads();
    const float rs = rsqrtf(81.f * 521.f);
    for (int idx = t; idx < N_NODES * C_CLS; idx += 512) {
        const int i = idx / C_CLS, c = idx - i * C_CLS;
        float v;
        if (i < NSUP) v = sQ[c] * rs + hlab[i / PER][c] * (1.0f / 81.0f);
        else          v = sS[c] * rs + hlab[C_CLS + i - NSUP][c] * (1.0f / 521.0f);
        out[idx] = v + blab[c];
    }
}

extern "C" void kernel_launch(void* const* d_in, const int* in_sizes, int n_in,
                              void* d_out, int out_size, void* d_ws, size_t ws_size,
                              hipStream_t stream) {
    (void)in_sizes; (void)n_in; (void)out_size; (void)ws_size;
    const float* f0   = (const float*)d_in[0];
    const float* f1   = (const float*)d_in[1];
    const float* Wf0  = (const float*)d_in[9];
    const float* bf0  = (const float*)d_in[10];
    const float* Wf1  = (const float*)d_in[11];
    const float* bf1  = (const float*)d_in[12];
    const float* Win  = (const float*)d_in[13];
    const float* bin  = (const float*)d_in[14];
    const float* Wl   = (const float*)d_in[15];
    const float* bl   = (const float*)d_in[16];
    const float* Wr   = (const float*)d_in[17];
    const float* br   = (const float*)d_in[18];
    const float* att  = (const float*)d_in[19];
    const float* bgat = (const float*)d_in[20];
    const float* cw   = (const float*)d_in[21];
    const float* cb   = (const float*)d_in[22];
    const float* Wlab = (const float*)d_in[23];
    const float* blab = (const float*)d_in[24];
    float* out = (float*)d_out;

    float* ws = (float*)d_ws;
    float* csump   = ws;            // [8][5][1024] = 40960
    float* cated85 = ws + 40960;    // [85][264] = 22440
    float* fc85    = ws + 63424;    // [85][512] = 43520
    float* hl85    = ws + 106944;   // [85][256] = 21760
    float* hr85    = ws + 128704;   // [85][256] = 21760 -> 150464 (~0.6 MB)

    csum_k   <<<dim3(4, 5, 8), 256, 0, stream>>>(f0, f1, csump);
    emb_k    <<<dim3(85, 2), 512, 0, stream>>>(f0, f1, csump, Wf0, Wf1, bf0, bf1, cated85);
    mm3_85_k <<<dim3(85, 3), 256, 0, stream>>>(cated85, Win, bin, Wl, bl, Wr, br,
                                               fc85, hl85, hr85);
    gat_k    <<<85, 256, 0, stream>>>(hl85, hr85, att, bgat, cw, cb, fc85);
    final85_k<<<1, 512, 0, stream>>>(fc85, Wlab, blab, out);
}